// Round 8
// baseline (126.375 us; speedup 1.0000x reference)
//
#include <hip/hip_runtime.h>

#define WALK_LEN 40
#define WINDOW   5
#define NPAIRS   370
#define BATCHSZ  512
#define NEGK     5
#define NPOS     (BATCHSZ * NPAIRS)        // 189440
#define EMB      128
#define NQ       (BATCHSZ * WALK_LEN)      // 20480 flat-walk rows
#define THREADS  512
#define GROUPS   (THREADS / 8)             // 64 8-lane groups
#define HALFP    185                       // pairs per block (2 blocks/batch)
#define NBLOCKS  (BATCHSZ * 2)             // 1024

struct PairTab { short src[NPAIRS]; short dst[NPAIRS]; };

constexpr PairTab make_pairs() {
    PairTab t{};
    int k = 0;
    for (int i = 0; i < WALK_LEN; ++i) {
        int lo = (i - WINDOW > 0) ? (i - WINDOW) : 0;
        for (int j = lo; j < i; ++j) { t.src[k] = (short)j; t.dst[k] = (short)i; ++k; }
        int hi = (i + 1 + WINDOW < WALK_LEN) ? (i + 1 + WINDOW) : WALK_LEN;
        for (int j = i + 1; j < hi; ++j) { t.src[k] = (short)j; t.dst[k] = (short)i; ++k; }
    }
    return t;
}

__constant__ PairTab g_pairs = make_pairs();

__device__ __forceinline__ unsigned short bf16rn(float f) {
    unsigned u = __float_as_uint(f);
    u += 0x7fffu + ((u >> 16) & 1u);
    return (unsigned short)(u >> 16);
}

// fast softplus: log(1+e^x) via raw v_exp/v_log; |err| ~1e-7 for x in [-6,6]
__device__ __forceinline__ float softplus_fast(float x) {
    const float e = __expf(x);          // v_mul + v_exp_f32
    return __logf(1.0f + e);            // v_add + v_log_f32 + v_mul
}

// dot of 8 bf16 pairs packed as uint4 (2 bf16 per uint), accumulated in f32
__device__ __forceinline__ float dot_u4(uint4 a, uint4 c) {
    float s = 0.f;
    #pragma unroll
    for (int i = 0; i < 4; ++i) {
        const unsigned av = (&a.x)[i], cv = (&c.x)[i];
        const float a0 = __uint_as_float(av << 16);
        const float a1 = __uint_as_float(av & 0xffff0000u);
        const float c0 = __uint_as_float(cv << 16);
        const float c1 = __uint_as_float(cv & 0xffff0000u);
        s = fmaf(a0, c0, s);
        s = fmaf(a1, c1, s);
    }
    return s;
}

// ---- phase 1: gather the 20480 flat-walk rows of each table into dense bf16 ----
__global__ __launch_bounds__(256) void dw_gather(
    const int*   __restrict__ walk,
    const float* __restrict__ nodeE,
    const float* __restrict__ ctxE,
    unsigned short* __restrict__ dN,
    unsigned short* __restrict__ dC)
{
    int idx = blockIdx.x * 256 + threadIdx.x;      // 0 .. 2*NQ*32-1
    const int is_ctx = (idx >= NQ * 32);
    if (is_ctx) idx -= NQ * 32;
    const int q = idx >> 5, c = idx & 31;
    const int row = walk[q];
    const float* src = (is_ctx ? ctxE : nodeE) + (size_t)row * EMB;
    const float4 v = *((const float4*)src + c);
    ushort4 o;
    o.x = bf16rn(v.x); o.y = bf16rn(v.y); o.z = bf16rn(v.z); o.w = bf16rn(v.w);
    unsigned short* dst = (is_ctx ? dC : dN) + (size_t)q * EMB;
    *((ushort4*)dst + c) = o;
}

// ---- phase 2: one block = half a batch (185 pairs). IDEMPOTENT (pure write
// of partial[blockIdx.x]) -> replayed 3x for phase-time attribution. ----
__global__ __launch_bounds__(THREADS) void dw_score(
    const int* __restrict__ negdst,                 // [NPOS*NEGK] -> dense row id
    const unsigned short* __restrict__ dN,
    const unsigned short* __restrict__ dC,
    float* __restrict__ partial)                    // [NBLOCKS]
{
    __shared__ unsigned int sN[WALK_LEN * 64];      // 10 KB (row = 64 uints = 256 B)
    __shared__ unsigned int sC[WALK_LEN * 64];      // 10 KB
    __shared__ float wsum[THREADS / 64];

    const int b    = blockIdx.x >> 1;
    const int half = blockIdx.x & 1;
    const int tid  = threadIdx.x;

    {
        const uint4* srcN = (const uint4*)(dN + (size_t)b * WALK_LEN * EMB);
        const uint4* srcC = (const uint4*)(dC + (size_t)b * WALK_LEN * EMB);
        for (int u = tid; u < WALK_LEN * 16; u += THREADS) {
            ((uint4*)sN)[u] = srcN[u];
            ((uint4*)sC)[u] = srcC[u];
        }
    }
    __syncthreads();

    const int lane8 = tid & 7;
    const int grp   = tid >> 3;           // 0..63
    const int jbase = half * HALFP;
    float acc = 0.0f;

    #pragma unroll 1
    for (int it = 0; it < 3; ++it) {
        const int jj = it * GROUPS + grp;           // 0..191
        if (jj < HALFP) {
            const int j = jbase + jj;
            const int p = b * NPAIRS + j;
            const int sj = g_pairs.src[j];
            const int dj = g_pairs.dst[j];

            const int* nb = negdst + p * NEGK;
            const int q0 = nb[0], q1 = nb[1], q2 = nb[2], q3 = nb[3], q4 = nb[4];

            const uint4* g0 = (const uint4*)(dC + (size_t)q0 * EMB);
            const uint4* g1 = (const uint4*)(dC + (size_t)q1 * EMB);
            const uint4* g2 = (const uint4*)(dC + (size_t)q2 * EMB);
            const uint4* g3 = (const uint4*)(dC + (size_t)q3 * EMB);
            const uint4* g4 = (const uint4*)(dC + (size_t)q4 * EMB);
            const uint4 x00 = g0[lane8], x01 = g0[lane8 + 8];
            const uint4 x10 = g1[lane8], x11 = g1[lane8 + 8];
            const uint4 x20 = g2[lane8], x21 = g2[lane8 + 8];
            const uint4 x30 = g3[lane8], x31 = g3[lane8 + 8];
            const uint4 x40 = g4[lane8], x41 = g4[lane8 + 8];

            const uint4* rN = (const uint4*)(sN + sj * 64);
            const uint4* rC = (const uint4*)(sC + dj * 64);
            const uint4* rS = (const uint4*)(sN + dj * 64);   // neg src row
            const uint4 a0 = rN[lane8], a1 = rN[lane8 + 8];
            const uint4 c0 = rC[lane8], c1 = rC[lane8 + 8];
            const uint4 n0 = rS[lane8], n1 = rS[lane8 + 8];

            // ---- positive ----
            {
                float d = dot_u4(a0, c0) + dot_u4(a1, c1);
                d += __shfl_xor(d, 1); d += __shfl_xor(d, 2); d += __shfl_xor(d, 4);
                const float s = fminf(6.f, fmaxf(-6.f, d));
                acc += softplus_fast(-s);
            }

            // ---- negatives ----
            #define NEG_TERM(xa, xb)                                              \
            do {                                                                  \
                float d = dot_u4(n0, xa) + dot_u4(n1, xb);                        \
                d += __shfl_xor(d, 1); d += __shfl_xor(d, 2); d += __shfl_xor(d, 4);\
                const float s = fminf(6.f, fmaxf(-6.f, d));                       \
                acc += softplus_fast(s);                                          \
            } while (0)
            NEG_TERM(x00, x01);
            NEG_TERM(x10, x11);
            NEG_TERM(x20, x21);
            NEG_TERM(x30, x31);
            NEG_TERM(x40, x41);
            #undef NEG_TERM
        }
    }

    acc += __shfl_xor(acc, 8);
    acc += __shfl_xor(acc, 16);
    acc += __shfl_xor(acc, 32);

    if ((tid & 63) == 0) wsum[tid >> 6] = acc;
    __syncthreads();
    if (tid == 0) {
        float tot = 0.f;
        #pragma unroll
        for (int w = 0; w < THREADS / 64; ++w) tot += wsum[w];
        partial[blockIdx.x] = tot;
    }
}

__global__ __launch_bounds__(256) void dw_reduce(
    const float* __restrict__ partial, float* __restrict__ out)
{
    const int tid = threadIdx.x;
    float s = 0.f;
    for (int i = tid; i < NBLOCKS; i += 256) s += partial[i];
    #pragma unroll
    for (int m = 1; m < 64; m <<= 1) s += __shfl_xor(s, m);
    __shared__ float wsum[4];
    if ((tid & 63) == 0) wsum[tid >> 6] = s;
    __syncthreads();
    if (tid == 0)
        out[0] = (wsum[0] + wsum[1] + wsum[2] + wsum[3]) * (1.0f / (float)NPOS);
}

extern "C" void kernel_launch(void* const* d_in, const int* in_sizes, int n_in,
                              void* d_out, int out_size, void* d_ws, size_t ws_size,
                              hipStream_t stream) {
    const int*   walk   = (const int*)d_in[0];
    const int*   negdst = (const int*)d_in[1];
    const float* nodeE  = (const float*)d_in[2];
    const float* ctxE   = (const float*)d_in[3];
    float*       out    = (float*)d_out;

    unsigned short* dN = (unsigned short*)d_ws;
    unsigned short* dC = dN + (size_t)NQ * EMB;
    float* part = (float*)((char*)d_ws + (16u << 20));   // 16 MB offset

    dw_gather<<<(2 * NQ * 32) / 256, 256, 0, stream>>>(walk, nodeE, ctxE, dN, dC);
    // dw_score is a pure/idempotent write of partial[] -> replay 3x to split
    // phase times from the single total: dur = G + 3*S + R  (R6: G + S + R).
    dw_score<<<NBLOCKS, THREADS, 0, stream>>>(negdst, dN, dC, part);
    dw_score<<<NBLOCKS, THREADS, 0, stream>>>(negdst, dN, dC, part);
    dw_score<<<NBLOCKS, THREADS, 0, stream>>>(negdst, dN, dC, part);
    dw_reduce<<<1, 256, 0, stream>>>(part, out);
}

// Round 10
// 39.029 us; speedup vs baseline: 3.2380x; 3.2380x over previous
//
#include <hip/hip_runtime.h>

#define WALK_LEN 40
#define WINDOW   5
#define NPAIRS   370
#define BATCHSZ  512
#define NEGK     5
#define NPOS     (BATCHSZ * NPAIRS)        // 189440
#define EMB      128
#define NQ       (BATCHSZ * WALK_LEN)      // 20480 flat-walk rows
#define THREADS  512
#define GROUPS   (THREADS / 8)             // 64 8-lane groups
#define HALFP    185                       // pairs per block (2 blocks/batch)
#define NBLOCKS  (BATCHSZ * 2)             // 1024

struct PairTab { short src[NPAIRS]; short dst[NPAIRS]; };

constexpr PairTab make_pairs() {
    PairTab t{};
    int k = 0;
    for (int i = 0; i < WALK_LEN; ++i) {
        int lo = (i - WINDOW > 0) ? (i - WINDOW) : 0;
        for (int j = lo; j < i; ++j) { t.src[k] = (short)j; t.dst[k] = (short)i; ++k; }
        int hi = (i + 1 + WINDOW < WALK_LEN) ? (i + 1 + WINDOW) : WALK_LEN;
        for (int j = i + 1; j < hi; ++j) { t.src[k] = (short)j; t.dst[k] = (short)i; ++k; }
    }
    return t;
}

__constant__ PairTab g_pairs = make_pairs();

__device__ __forceinline__ unsigned short bf16rn(float f) {
    unsigned u = __float_as_uint(f);
    u += 0x7fffu + ((u >> 16) & 1u);
    return (unsigned short)(u >> 16);
}

// fast softplus: log(1+e^x); |err| ~1e-7 for x in [-6,6]
__device__ __forceinline__ float softplus_fast(float x) {
    return __logf(1.0f + __expf(x));
}

// 8-lane-group butterfly sum: xor1/xor2 via quad_perm DPP (VALU-only),
// xor4 via one ds_swizzle. Replaces 3 x ds_bpermute.
template <int CTRL>
__device__ __forceinline__ float dpp_qperm_add(float x) {
    int y = __builtin_amdgcn_update_dpp(0, __float_as_int(x), CTRL, 0xF, 0xF, true);
    return x + __int_as_float(y);
}
__device__ __forceinline__ float grp8_sum(float d) {
    d = dpp_qperm_add<0xB1>(d);    // quad_perm [1,0,3,2] == xor 1
    d = dpp_qperm_add<0x4E>(d);    // quad_perm [2,3,0,1] == xor 2
    int y = __builtin_amdgcn_ds_swizzle(__float_as_int(d), 0x101F); // xor 4
    return d + __int_as_float(y);
}

// unpack uint4 (8 bf16) -> 8 f32 (static indices -> registers)
#define UNPACK_U4(u, f, base)                                         \
    do {                                                              \
        _Pragma("unroll")                                             \
        for (int _i = 0; _i < 4; ++_i) {                              \
            const unsigned _v = (&(u).x)[_i];                         \
            (f)[(base) + 2 * _i]     = __uint_as_float(_v << 16);     \
            (f)[(base) + 2 * _i + 1] = __uint_as_float(_v & 0xffff0000u); \
        }                                                             \
    } while (0)

// dot of pre-unpacked 16 floats against packed rows xa,xb: 4 parallel fma chains
__device__ __forceinline__ float dot_pk(const float* nf, uint4 xa, uint4 xb) {
    float s0 = 0.f, s1 = 0.f, s2 = 0.f, s3 = 0.f;
    #pragma unroll
    for (int i = 0; i < 4; ++i) {
        const unsigned v = (&xa.x)[i];
        s0 = fmaf(__uint_as_float(v << 16),          nf[2 * i],     s0);
        s1 = fmaf(__uint_as_float(v & 0xffff0000u),  nf[2 * i + 1], s1);
    }
    #pragma unroll
    for (int i = 0; i < 4; ++i) {
        const unsigned v = (&xb.x)[i];
        s2 = fmaf(__uint_as_float(v << 16),          nf[8 + 2 * i],     s2);
        s3 = fmaf(__uint_as_float(v & 0xffff0000u),  nf[8 + 2 * i + 1], s3);
    }
    return (s0 + s1) + (s2 + s3);
}

// ---- phase 1: gather flat-walk rows into dense bf16; block 0 zeroes out ----
__global__ __launch_bounds__(256) void dw_gather(
    const int*   __restrict__ walk,
    const float* __restrict__ nodeE,
    const float* __restrict__ ctxE,
    unsigned short* __restrict__ dN,
    unsigned short* __restrict__ dC,
    float* __restrict__ out)
{
    if (blockIdx.x == 0 && threadIdx.x == 0) out[0] = 0.f;
    int idx = blockIdx.x * 256 + threadIdx.x;      // 0 .. 2*NQ*32-1
    const int is_ctx = (idx >= NQ * 32);
    if (is_ctx) idx -= NQ * 32;
    const int q = idx >> 5, c = idx & 31;
    const int row = walk[q];
    const float* src = (is_ctx ? ctxE : nodeE) + (size_t)row * EMB;
    const float4 v = *((const float4*)src + c);
    ushort4 o;
    o.x = bf16rn(v.x); o.y = bf16rn(v.y); o.z = bf16rn(v.z); o.w = bf16rn(v.w);
    unsigned short* dst = (is_ctx ? dC : dN) + (size_t)q * EMB;
    *((ushort4*)dst + c) = o;
}

// ---- phase 2: one block = half a batch (185 pairs) ----
__global__ __launch_bounds__(THREADS) void dw_score(
    const int* __restrict__ negdst,                 // [NPOS*NEGK] -> dense row id
    const unsigned short* __restrict__ dN,
    const unsigned short* __restrict__ dC,
    float* __restrict__ out)
{
    __shared__ unsigned int sN[WALK_LEN * 64];      // 10 KB (row = 256 B)
    __shared__ unsigned int sC[WALK_LEN * 64];      // 10 KB
    __shared__ float wsum[THREADS / 64];

    const int b    = blockIdx.x >> 1;
    const int half = blockIdx.x & 1;
    const int tid  = threadIdx.x;

    {
        const uint4* srcN = (const uint4*)(dN + (size_t)b * WALK_LEN * EMB);
        const uint4* srcC = (const uint4*)(dC + (size_t)b * WALK_LEN * EMB);
        for (int u = tid; u < WALK_LEN * 16; u += THREADS) {
            ((uint4*)sN)[u] = srcN[u];
            ((uint4*)sC)[u] = srcC[u];
        }
    }
    __syncthreads();

    const int lane8 = tid & 7;
    const int grp   = tid >> 3;           // 0..63
    const int jbase = half * HALFP;
    float acc = 0.0f;

    #pragma unroll 1
    for (int it = 0; it < 3; ++it) {
        const int jj = it * GROUPS + grp;           // 0..191
        if (jj < HALFP) {
            const int j = jbase + jj;
            const int p = b * NPAIRS + j;
            const int sj = g_pairs.src[j];
            const int dj = g_pairs.dst[j];

            const int* nb = negdst + p * NEGK;
            const int q0 = nb[0], q1 = nb[1], q2 = nb[2], q3 = nb[3], q4 = nb[4];

            // issue all 10 neg-row loads up front (MLP)
            const uint4* g0 = (const uint4*)(dC + (size_t)q0 * EMB);
            const uint4* g1 = (const uint4*)(dC + (size_t)q1 * EMB);
            const uint4* g2 = (const uint4*)(dC + (size_t)q2 * EMB);
            const uint4* g3 = (const uint4*)(dC + (size_t)q3 * EMB);
            const uint4* g4 = (const uint4*)(dC + (size_t)q4 * EMB);
            const uint4 x00 = g0[lane8], x01 = g0[lane8 + 8];
            const uint4 x10 = g1[lane8], x11 = g1[lane8 + 8];
            const uint4 x20 = g2[lane8], x21 = g2[lane8 + 8];
            const uint4 x30 = g3[lane8], x31 = g3[lane8 + 8];
            const uint4 x40 = g4[lane8], x41 = g4[lane8 + 8];

            const uint4* rN = (const uint4*)(sN + sj * 64);
            const uint4* rC = (const uint4*)(sC + dj * 64);
            const uint4* rS = (const uint4*)(sN + dj * 64);   // neg src row
            const uint4 a0 = rN[lane8], a1 = rN[lane8 + 8];
            const uint4 c0 = rC[lane8], c1 = rC[lane8 + 8];
            const uint4 n0 = rS[lane8], n1 = rS[lane8 + 8];

            // ---- positive: unpack a once, dot against packed c ----
            {
                float af[16];
                UNPACK_U4(a0, af, 0);
                UNPACK_U4(a1, af, 8);
                float d = grp8_sum(dot_pk(af, c0, c1));
                const float s = fminf(6.f, fmaxf(-6.f, d));
                acc += softplus_fast(-s);
            }

            // ---- negatives: unpack n ONCE, 5 tree-dots against packed x ----
            {
                float nf[16];
                UNPACK_U4(n0, nf, 0);
                UNPACK_U4(n1, nf, 8);
                float d0 = grp8_sum(dot_pk(nf, x00, x01));
                float d1 = grp8_sum(dot_pk(nf, x10, x11));
                float d2 = grp8_sum(dot_pk(nf, x20, x21));
                float d3 = grp8_sum(dot_pk(nf, x30, x31));
                float d4 = grp8_sum(dot_pk(nf, x40, x41));
                acc += softplus_fast(fminf(6.f, fmaxf(-6.f, d0)));
                acc += softplus_fast(fminf(6.f, fmaxf(-6.f, d1)));
                acc += softplus_fast(fminf(6.f, fmaxf(-6.f, d2)));
                acc += softplus_fast(fminf(6.f, fmaxf(-6.f, d3)));
                acc += softplus_fast(fminf(6.f, fmaxf(-6.f, d4)));
            }
        }
    }

    // group sums -> wave sum (each group counted once)
    acc += __shfl_xor(acc, 8);
    acc += __shfl_xor(acc, 16);
    acc += __shfl_xor(acc, 32);

    if ((tid & 63) == 0) wsum[tid >> 6] = acc;
    __syncthreads();
    if (tid == 0) {
        float tot = 0.f;
        #pragma unroll
        for (int w = 0; w < THREADS / 64; ++w) tot += wsum[w];
        atomicAdd(out, tot * (1.0f / (float)NPOS));
    }
}

extern "C" void kernel_launch(void* const* d_in, const int* in_sizes, int n_in,
                              void* d_out, int out_size, void* d_ws, size_t ws_size,
                              hipStream_t stream) {
    const int*   walk   = (const int*)d_in[0];
    const int*   negdst = (const int*)d_in[1];
    const float* nodeE  = (const float*)d_in[2];
    const float* ctxE   = (const float*)d_in[3];
    float*       out    = (float*)d_out;

    unsigned short* dN = (unsigned short*)d_ws;
    unsigned short* dC = dN + (size_t)NQ * EMB;

    dw_gather<<<(2 * NQ * 32) / 256, 256, 0, stream>>>(walk, nodeE, ctxE, dN, dC, out);
    dw_score<<<NBLOCKS, THREADS, 0, stream>>>(negdst, dN, dC, out);
}